// Round 13
// baseline (244.563 us; speedup 1.0000x reference)
//
#include <hip/hip_runtime.h>
#include <hip/hip_fp16.h>

// Problem constants (fixed by the reference)
#define S_N 32
#define O_N 64
#define A_N 8
#define R_N 8
#define B_N 1024
#define T_N 128

// Workspace layout (float-index offsets):
//  [0, 4096)      TH : packed fp16 transitions (16 KB), as uint4 entries
//  [4096, 6144)   OT[o][s]     = P(o|s)
//  [6144, 8192)   RA[r*8+a][s] = P(r|s)*P(a|s)
//  [8192, 8448)   RT[r][s]     = P(r|s)
//  [8448, 8480)   PI[s]
//  [13000, 14024) ablation scratch
#define OT_OFF   4096
#define RA_OFF   6144
#define RT_OFF   8192
#define PI_OFF   8448
#define ABL_OFF  13000

// LDS emission block (floats) — contiguous image of ws[4096..8480)
#define L_OT 0
#define L_RA 2048
#define L_RT 4096
#define L_PI 4352
#define L_N  4384

__global__ __launch_bounds__(256) void tam_prep(
    const float* __restrict__ params_s,
    const float* __restrict__ params_s_sa,
    const float* __restrict__ params_o_s,
    const float* __restrict__ params_r_s,
    const float* __restrict__ params_a_s,
    float* __restrict__ ws)
{
    const int tid = threadIdx.x;
    if (blockIdx.x == 0) {
        const int s = tid >> 3, a = tid & 7;
        const float* row = params_s_sa + (s * A_N + a) * S_N;
        float p[32];
        #pragma unroll
        for (int i = 0; i < 8; ++i) {
            float4 v = reinterpret_cast<const float4*>(row)[i];
            p[4*i]=v.x; p[4*i+1]=v.y; p[4*i+2]=v.z; p[4*i+3]=v.w;
        }
        float mx = p[0];
        #pragma unroll
        for (int i = 1; i < 32; ++i) mx = fmaxf(mx, p[i]);
        float sum = 0.f;
        #pragma unroll
        for (int i = 0; i < 32; ++i) { p[i] = __expf(p[i] - mx); sum += p[i]; }
        const float inv = 1.0f / sum;
        __half* wsh = reinterpret_cast<__half*>(ws);
        __half* base = wsh + (size_t)((a * 4 + (s >> 3)) * 32) * 8 + (s & 7);
        #pragma unroll
        for (int sl = 0; sl < 32; ++sl) base[sl * 8] = __float2half_rn(p[sl] * inv);
    } else {
        __shared__ float sRT[256], sAT[256];
        if (tid < 32) {
            const int s = tid;
            const float* row = params_o_s + s * O_N;
            float p[64];
            #pragma unroll
            for (int i = 0; i < 16; ++i) {
                float4 v = reinterpret_cast<const float4*>(row)[i];
                p[4*i]=v.x; p[4*i+1]=v.y; p[4*i+2]=v.z; p[4*i+3]=v.w;
            }
            float mx = p[0];
            #pragma unroll
            for (int i = 1; i < 64; ++i) mx = fmaxf(mx, p[i]);
            float sum = 0.f;
            #pragma unroll
            for (int i = 0; i < 64; ++i) { p[i] = __expf(p[i] - mx); sum += p[i]; }
            const float inv = 1.0f / sum;
            #pragma unroll
            for (int o = 0; o < 64; ++o) ws[OT_OFF + o * 32 + s] = p[o] * inv;
        } else if (tid < 64) {
            const int s = tid - 32;
            const float* row = params_r_s + s * R_N;
            float p[8];
            #pragma unroll
            for (int i = 0; i < 2; ++i) {
                float4 v = reinterpret_cast<const float4*>(row)[i];
                p[4*i]=v.x; p[4*i+1]=v.y; p[4*i+2]=v.z; p[4*i+3]=v.w;
            }
            float mx = p[0];
            #pragma unroll
            for (int i = 1; i < 8; ++i) mx = fmaxf(mx, p[i]);
            float sum = 0.f;
            #pragma unroll
            for (int i = 0; i < 8; ++i) { p[i] = __expf(p[i] - mx); sum += p[i]; }
            const float inv = 1.0f / sum;
            #pragma unroll
            for (int r = 0; r < 8; ++r) {
                const float v = p[r] * inv;
                ws[RT_OFF + r * 32 + s] = v;
                sRT[r * 32 + s] = v;
            }
        } else if (tid < 96) {
            const int s = tid - 64;
            const float* row = params_a_s + s * A_N;
            float p[8];
            #pragma unroll
            for (int i = 0; i < 2; ++i) {
                float4 v = reinterpret_cast<const float4*>(row)[i];
                p[4*i]=v.x; p[4*i+1]=v.y; p[4*i+2]=v.z; p[4*i+3]=v.w;
            }
            float mx = p[0];
            #pragma unroll
            for (int i = 1; i < 8; ++i) mx = fmaxf(mx, p[i]);
            float sum = 0.f;
            #pragma unroll
            for (int i = 0; i < 8; ++i) { p[i] = __expf(p[i] - mx); sum += p[i]; }
            const float inv = 1.0f / sum;
            #pragma unroll
            for (int a = 0; a < 8; ++a) sAT[a * 32 + s] = p[a] * inv;
        } else if (tid < 128) {
            const int s = tid - 96;
            float p[32];
            #pragma unroll
            for (int i = 0; i < 8; ++i) {
                float4 v = reinterpret_cast<const float4*>(params_s)[i];
                p[4*i]=v.x; p[4*i+1]=v.y; p[4*i+2]=v.z; p[4*i+3]=v.w;
            }
            float mx = p[0];
            #pragma unroll
            for (int i = 1; i < 32; ++i) mx = fmaxf(mx, p[i]);
            float sum = 0.f;
            #pragma unroll
            for (int i = 0; i < 32; ++i) { p[i] = __expf(p[i] - mx); sum += p[i]; }
            ws[PI_OFF + s] = p[s] / sum;
        }
        __syncthreads();
        #pragma unroll 1
        for (int i = tid; i < 2048; i += 256) {
            const int sl = i & 31, ra = i >> 5;
            ws[RA_OFF + i] = sRT[(ra >> 3) * 32 + sl] * sAT[(ra & 7) * 32 + sl];
        }
    }
}

#define RLI(v, l) __builtin_amdgcn_readlane((v), (l))
#define RLF(v, l) __int_as_float(__builtin_amdgcn_readlane(__float_as_int(v), (l)))

static __device__ __forceinline__ __half2 u2h(unsigned u) {
    union { unsigned u; __half2 h; } c; c.u = u; return c.h;
}

// Load action A_'s 32x32 fp16 transition column sl: 4 x ds_read_b128
#define LOADTH(TH, A_) {                                                     \
    const uint4* p_ = sTH + ((A_) << 7) + sl;                                \
    const uint4 q0_ = p_[0], q1_ = p_[32], q2_ = p_[64], q3_ = p_[96];       \
    TH[0]=q0_.x;  TH[1]=q0_.y;  TH[2]=q0_.z;  TH[3]=q0_.w;                   \
    TH[4]=q1_.x;  TH[5]=q1_.y;  TH[6]=q1_.z;  TH[7]=q1_.w;                   \
    TH[8]=q2_.x;  TH[9]=q2_.y;  TH[10]=q2_.z; TH[11]=q2_.w;                  \
    TH[12]=q3_.x; TH[13]=q3_.y; TH[14]=q3_.z; TH[15]=q3_.w; }

#define LOADE(EO, ERA, PKW) {                                                \
    const unsigned pk_ = (PKW);                                              \
    EO  = sE[(int)(pk_ & 63u) * 32 + sl];                                    \
    ERA = sE[eBase + (int)((pk_ >> 6) & 7u) * eMulR                          \
                   + (int)((pk_ >> 9) & 7u) * eMulA + sl]; }

#define STEP(EO, ERA, TH) {                                                  \
    const float wv = u * (EO) * (ERA);                                       \
    const float w0 =RLF(wv,0),  w1 =RLF(wv,1),  w2 =RLF(wv,2),  w3 =RLF(wv,3),  \
                w4 =RLF(wv,4),  w5 =RLF(wv,5),  w6 =RLF(wv,6),  w7 =RLF(wv,7),  \
                w8 =RLF(wv,8),  w9 =RLF(wv,9),  w10=RLF(wv,10), w11=RLF(wv,11), \
                w12=RLF(wv,12), w13=RLF(wv,13), w14=RLF(wv,14), w15=RLF(wv,15), \
                w16=RLF(wv,16), w17=RLF(wv,17), w18=RLF(wv,18), w19=RLF(wv,19), \
                w20=RLF(wv,20), w21=RLF(wv,21), w22=RLF(wv,22), w23=RLF(wv,23), \
                w24=RLF(wv,24), w25=RLF(wv,25), w26=RLF(wv,26), w27=RLF(wv,27), \
                w28=RLF(wv,28), w29=RLF(wv,29), w30=RLF(wv,30), w31=RLF(wv,31); \
    float c0 = 0.f, c1 = 0.f, c2 = 0.f, c3 = 0.f;                            \
    c0=fmaf(w0, __low2float(u2h(TH[0])), c0); c1=fmaf(w1, __high2float(u2h(TH[0])), c1); \
    c2=fmaf(w2, __low2float(u2h(TH[1])), c2); c3=fmaf(w3, __high2float(u2h(TH[1])), c3); \
    c0=fmaf(w4, __low2float(u2h(TH[2])), c0); c1=fmaf(w5, __high2float(u2h(TH[2])), c1); \
    c2=fmaf(w6, __low2float(u2h(TH[3])), c2); c3=fmaf(w7, __high2float(u2h(TH[3])), c3); \
    c0=fmaf(w8, __low2float(u2h(TH[4])), c0); c1=fmaf(w9, __high2float(u2h(TH[4])), c1); \
    c2=fmaf(w10,__low2float(u2h(TH[5])), c2); c3=fmaf(w11,__high2float(u2h(TH[5])), c3); \
    c0=fmaf(w12,__low2float(u2h(TH[6])), c0); c1=fmaf(w13,__high2float(u2h(TH[6])), c1); \
    c2=fmaf(w14,__low2float(u2h(TH[7])), c2); c3=fmaf(w15,__high2float(u2h(TH[7])), c3); \
    c0=fmaf(w16,__low2float(u2h(TH[8])), c0); c1=fmaf(w17,__high2float(u2h(TH[8])), c1); \
    c2=fmaf(w18,__low2float(u2h(TH[9])), c2); c3=fmaf(w19,__high2float(u2h(TH[9])), c3); \
    c0=fmaf(w20,__low2float(u2h(TH[10])),c0); c1=fmaf(w21,__high2float(u2h(TH[10])),c1); \
    c2=fmaf(w22,__low2float(u2h(TH[11])),c2); c3=fmaf(w23,__high2float(u2h(TH[11])),c3); \
    c0=fmaf(w24,__low2float(u2h(TH[12])),c0); c1=fmaf(w25,__high2float(u2h(TH[12])),c1); \
    c2=fmaf(w26,__low2float(u2h(TH[13])),c2); c3=fmaf(w27,__high2float(u2h(TH[13])),c3); \
    c0=fmaf(w28,__low2float(u2h(TH[14])),c0); c1=fmaf(w29,__high2float(u2h(TH[14])),c1); \
    c2=fmaf(w30,__low2float(u2h(TH[15])),c2); c3=fmaf(w31,__high2float(u2h(TH[15])),c3); \
    u = (c0 + c1) + (c2 + c3); }

// 4 waves per block, ONE episode per wave — the validated r7 main kernel.
__global__ __launch_bounds__(256, 4) void tam_main(
    const float* __restrict__ regime,
    const int*   __restrict__ obs,
    const int*   __restrict__ rewards,
    const int*   __restrict__ dones_i,
    const int*   __restrict__ actions,
    const float* __restrict__ ws,
    float* __restrict__ out)
{
    __shared__ uint4 sTH[1024];
    __shared__ float sE[L_N];
    const int tid  = threadIdx.x;
    const int lane = tid & 63;
    const int wid  = tid >> 6;
    const int sl   = lane & 31;
    const int b    = blockIdx.x * 4 + wid;

    {
        const uint4* gt = reinterpret_cast<const uint4*>(ws);
        #pragma unroll
        for (int i = 0; i < 4; ++i) sTH[tid + i * 256] = gt[tid + i * 256];
        const float4* ge = reinterpret_cast<const float4*>(ws + OT_OFF);
        float4* s4 = reinterpret_cast<float4*>(sE);
        #pragma unroll 1
        for (int i = tid; i < L_N / 4; i += 256) s4[i] = ge[i];
    }
    __syncthreads();

    const int t0 = 2 * lane, t1 = 2 * lane + 1;
    const int o0 = obs[t0 * B_N + b],      o1 = obs[t1 * B_N + b];
    const int r0 = rewards[t0 * B_N + b],  r1 = rewards[t1 * B_N + b];
    const int a0 = actions[t0 * B_N + b],  a1 = actions[t1 * B_N + b];
    const int d0 = dones_i[t0 * B_N + b],  d1 = dones_i[t1 * B_N + b];
    const int vpk = (o0 | (r0 << 6) | (a0 << 9)) |
                    ((o1 | (r1 << 6) | (a1 << 9)) << 16);

    const unsigned long long mE = __ballot(d0 != 0);
    const unsigned long long mO = __ballot(d1 != 0);
    const int tE = mE ? 2 * __builtin_ctzll(mE)     : (1 << 30);
    const int tO = mO ? 2 * __builtin_ctzll(mO) + 1 : (1 << 30);
    const int tstar  = tE < tO ? tE : tO;
    const int nsteps = tstar < 128 ? tstar : 128;

    const bool skipA = (regime[b] == 1.0f);
    const int eBase = skipA ? L_RT : L_RA;
    const int eMulR = skipA ? 32 : 256;
    const int eMulA = skipA ? 0 : 32;

    float u = sE[L_PI + sl];
    int ksum = 0;
    float eoA, eraA, eoB, eraB;
    unsigned thA[16], thB[16];

    unsigned pkc = (unsigned)RLI(vpk, 0);
    unsigned pkn = (unsigned)RLI(vpk, 1);
    LOADE(eoA, eraA, pkc & 0xffffu);
    LOADTH(thA, (int)((pkc >> 9) & 7u));

    const int npairs = nsteps >> 1;
    #pragma unroll 1
    for (int i = 0; i < npairs; ++i) {
        LOADE(eoB, eraB, pkc >> 16);
        LOADTH(thB, (int)((pkc >> 25) & 7u));
        STEP(eoA, eraA, thA);
        LOADE(eoA, eraA, pkn & 0xffffu);
        LOADTH(thA, (int)((pkn >> 9) & 7u));
        STEP(eoB, eraB, thB);
        pkc = pkn;
        pkn = (unsigned)RLI(vpk, i + 2);
        const int ub = RLI(__float_as_int(u), 0);
        const int kb = (ub >> 23) & 255;
        u *= __int_as_float((254 - kb) << 23);
        ksum += kb - 127;
    }

    if (nsteps & 1) {
        STEP(eoA, eraA, thA);
    }

    {
        const int e  = nsteps;
        const int oe = obs[e * B_N + b];
        const int re = rewards[e * B_N + b];
        const float eo = sE[L_OT + oe * 32 + sl];
        const float rt = sE[L_RT + re * 32 + sl];
        float t = u * eo * rt;
        t += __shfl_xor(t, 1, 32);
        t += __shfl_xor(t, 2, 32);
        t += __shfl_xor(t, 4, 32);
        t += __shfl_xor(t, 8, 32);
        t += __shfl_xor(t, 16, 32);
        const float result = (float)ksum * 0.69314718055994531f + __logf(t);
        if (lane == 0) out[b] = result;
    }
}

// ---------------- Ablation kernels (diagnostic; write to ws scratch) -------
// MODE bit0 = per-step LDS loads; bit1 = readlane broadcasts; bit2 = fma chain
template<int MODE, int REPS>
__global__ __launch_bounds__(256) void tam_abl(
    const float* __restrict__ ws,
    float* __restrict__ scratch)
{
    __shared__ uint4 sTH[1024];
    __shared__ float sE[L_N];
    const int tid  = threadIdx.x;
    const int lane = tid & 63;
    const int sl   = lane & 31;

    {
        const uint4* gt = reinterpret_cast<const uint4*>(ws);
        #pragma unroll
        for (int i = 0; i < 4; ++i) sTH[tid + i * 256] = gt[tid + i * 256];
        const float4* ge = reinterpret_cast<const float4*>(ws + OT_OFF);
        float4* s4 = reinterpret_cast<float4*>(sE);
        #pragma unroll 1
        for (int i = tid; i < L_N / 4; i += 256) s4[i] = ge[i];
    }
    __syncthreads();

    float u = sE[L_PI + sl];
    int ksum = 0;

    unsigned thP[16];
    LOADTH(thP, 0);                       // fixed T for no-loads modes
    const float eP = 0.9921875f;          // fixed E for no-loads modes

    #pragma unroll 1
    for (int rep = 0; rep < REPS; ++rep) {
        #pragma unroll 1
        for (int i = 0; i < 64; ++i) {
            #pragma unroll
            for (int half = 0; half < 2; ++half) {
                const int t = 2 * i + half;
                unsigned th[16];
                float Ee;
                if constexpr ((MODE & 1) != 0) {
                    // synthetic loop-varying indices (wave-uniform like baseline)
                    const int a_ = (t + rep) & 7;
                    const int o_ = (t * 7 + rep) & 63;
                    const int r_ = (t * 3) & 7;
                    Ee = sE[L_OT + o_ * 32 + sl] *
                         sE[L_RA + r_ * 256 + a_ * 32 + sl];
                    LOADTH(th, a_);
                } else {
                    Ee = eP;
                    #pragma unroll
                    for (int q = 0; q < 16; ++q) th[q] = thP[q];
                }
                const float wv = u * Ee;
                int kk[32];
                if constexpr ((MODE & 2) != 0) {
                    #pragma unroll
                    for (int s = 0; s < 32; ++s)
                        kk[s] = RLI(__float_as_int(wv), s);
                } else {
                    #pragma unroll
                    for (int s = 0; s < 32; ++s) kk[s] = __float_as_int(wv);
                }
                if constexpr ((MODE & 4) != 0) {
                    float c[4] = {0.f, 0.f, 0.f, 0.f};
                    #pragma unroll
                    for (int q = 0; q < 16; ++q) {
                        c[(2 * q) & 3] = fmaf(__int_as_float(kk[2 * q]),
                                              __low2float(u2h(th[q])),
                                              c[(2 * q) & 3]);
                        c[(2 * q + 1) & 3] = fmaf(__int_as_float(kk[2 * q + 1]),
                                                  __high2float(u2h(th[q])),
                                                  c[(2 * q + 1) & 3]);
                    }
                    u = (c[0] + c[1]) + (c[2] + c[3]);
                } else {
                    // keep readlanes / loads alive without consuming VALU
                    if constexpr ((MODE & 2) != 0) {
                        #pragma unroll
                        for (int s = 0; s < 32; ++s)
                            asm volatile("" :: "s"(kk[s]));
                    } else {
                        asm volatile("" :: "v"(kk[0]));
                    }
                    #pragma unroll
                    for (int q = 0; q < 16; ++q)
                        asm volatile("" :: "v"(th[q]));
                    u = wv;
                }
            }
            // rescale — part of the skeleton in every mode
            const int ub = RLI(__float_as_int(u), 0);
            const int kb = (ub >> 23) & 255;
            u *= __int_as_float((254 - kb) << 23);
            ksum += kb - 127;
        }
    }
    if (lane == 0)
        scratch[blockIdx.x * 4 + (tid >> 6)] = u + (float)ksum * 1e-30f;
}

extern "C" void kernel_launch(void* const* d_in, const int* in_sizes, int n_in,
                              void* d_out, int out_size, void* d_ws, size_t ws_size,
                              hipStream_t stream) {
    (void)in_sizes; (void)n_in; (void)out_size; (void)ws_size;
    const float* regime      = (const float*)d_in[0];
    const int*   obs         = (const int*)d_in[1];
    const int*   rewards     = (const int*)d_in[2];
    const int*   dones_i     = (const int*)d_in[3];
    const int*   actions     = (const int*)d_in[4];
    const float* params_s    = (const float*)d_in[5];
    const float* params_s_sa = (const float*)d_in[6];
    const float* params_o_s  = (const float*)d_in[7];
    const float* params_r_s  = (const float*)d_in[8];
    const float* params_a_s  = (const float*)d_in[9];
    float* ws  = (float*)d_ws;
    float* out = (float*)d_out;

    tam_prep<<<2, 256, 0, stream>>>(params_s, params_s_sa, params_o_s,
                                    params_r_s, params_a_s, ws);
    tam_main<<<256, 256, 0, stream>>>(regime, obs, rewards, dones_i, actions, ws, out);

    // Diagnostic ablations (scratch-only; output above is the graded result)
    float* scr = ws + ABL_OFF;
    tam_abl<7, 2><<<256, 256, 0, stream>>>(ws, scr);   // K0 full
    tam_abl<6, 2><<<256, 256, 0, stream>>>(ws, scr);   // K1 no LDS loads
    tam_abl<5, 2><<<256, 256, 0, stream>>>(ws, scr);   // K2 no broadcasts
    tam_abl<3, 2><<<256, 256, 0, stream>>>(ws, scr);   // K3 no fma chain
    tam_abl<0, 8><<<256, 256, 0, stream>>>(ws, scr);   // K4 skeleton
}

// Round 14
// 32.365 us; speedup vs baseline: 7.5565x; 7.5565x over previous
//
#include <hip/hip_runtime.h>

// Problem constants (fixed by the reference)
#define S_N 32
#define O_N 64
#define A_N 8
#define R_N 8
#define B_N 1024
#define T_N 128

// Workspace layout (float-index offsets):
//  [0, 4096)      TB : bf16 transitions in MFMA B-fragment layout (16 KB).
//                 For action a, frag f (=dest half), lane l (0..63):
//                 uint4 at [a*128 + f*64 + l] holds 8 bf16, elem j =
//                 T[src = 8*(l>>4)+j][a][dest = (l&15)+16f]
//  [4096, 6144)   OT[o][s]     = P(o|s)
//  [6144, 8192)   RA[r*8+a][s] = P(r|s)*P(a|s)
//  [8192, 8448)   RT[r][s]     = P(r|s)
//  [8448, 8480)   PI[s]
#define OT_OFF   4096
#define RA_OFF   6144
#define RT_OFF   8192
#define PI_OFF   8448

// LDS emission block (floats) — contiguous image of ws[4096..8480)
#define L_OT 0
#define L_RA 2048
#define L_RT 4096
#define L_PI 4352
#define L_N  4384

typedef float f32x4 __attribute__((ext_vector_type(4)));
typedef short bf16x8 __attribute__((ext_vector_type(8)));

__global__ __launch_bounds__(256) void tam_prep(
    const float* __restrict__ params_s,
    const float* __restrict__ params_s_sa,
    const float* __restrict__ params_o_s,
    const float* __restrict__ params_r_s,
    const float* __restrict__ params_a_s,
    float* __restrict__ ws)
{
    const int tid = threadIdx.x;
    if (blockIdx.x == 0) {
        // Transitions: one (s,a) row softmax each; scatter bf16 into the
        // MFMA B-frag layout described above.
        const int s = tid >> 3, a = tid & 7;
        const float* row = params_s_sa + (s * A_N + a) * S_N;
        float p[32];
        #pragma unroll
        for (int i = 0; i < 8; ++i) {
            float4 v = reinterpret_cast<const float4*>(row)[i];
            p[4*i]=v.x; p[4*i+1]=v.y; p[4*i+2]=v.z; p[4*i+3]=v.w;
        }
        float mx = p[0];
        #pragma unroll
        for (int i = 1; i < 32; ++i) mx = fmaxf(mx, p[i]);
        float sum = 0.f;
        #pragma unroll
        for (int i = 0; i < 32; ++i) { p[i] = __expf(p[i] - mx); sum += p[i]; }
        const float inv = 1.0f / sum;
        unsigned short* wsh = reinterpret_cast<unsigned short*>(ws);
        #pragma unroll
        for (int d = 0; d < 32; ++d) {
            const unsigned bits = __float_as_uint(p[d] * inv) + 0x8000u;
            const int idx = ((a * 2 + (d >> 4)) * 64 + 16 * (s >> 3) + (d & 15)) * 8
                            + (s & 7);
            wsh[idx] = (unsigned short)(bits >> 16);
        }
    } else {
        __shared__ float sRT[256], sAT[256];
        if (tid < 32) {
            // observation emission: softmax over O (64) per state; OT[o][s]
            const int s = tid;
            const float* row = params_o_s + s * O_N;
            float p[64];
            #pragma unroll
            for (int i = 0; i < 16; ++i) {
                float4 v = reinterpret_cast<const float4*>(row)[i];
                p[4*i]=v.x; p[4*i+1]=v.y; p[4*i+2]=v.z; p[4*i+3]=v.w;
            }
            float mx = p[0];
            #pragma unroll
            for (int i = 1; i < 64; ++i) mx = fmaxf(mx, p[i]);
            float sum = 0.f;
            #pragma unroll
            for (int i = 0; i < 64; ++i) { p[i] = __expf(p[i] - mx); sum += p[i]; }
            const float inv = 1.0f / sum;
            #pragma unroll
            for (int o = 0; o < 64; ++o) ws[OT_OFF + o * 32 + s] = p[o] * inv;
        } else if (tid < 64) {
            // reward emission: RT[r][s]
            const int s = tid - 32;
            const float* row = params_r_s + s * R_N;
            float p[8];
            #pragma unroll
            for (int i = 0; i < 2; ++i) {
                float4 v = reinterpret_cast<const float4*>(row)[i];
                p[4*i]=v.x; p[4*i+1]=v.y; p[4*i+2]=v.z; p[4*i+3]=v.w;
            }
            float mx = p[0];
            #pragma unroll
            for (int i = 1; i < 8; ++i) mx = fmaxf(mx, p[i]);
            float sum = 0.f;
            #pragma unroll
            for (int i = 0; i < 8; ++i) { p[i] = __expf(p[i] - mx); sum += p[i]; }
            const float inv = 1.0f / sum;
            #pragma unroll
            for (int r = 0; r < 8; ++r) {
                const float v = p[r] * inv;
                ws[RT_OFF + r * 32 + s] = v;
                sRT[r * 32 + s] = v;
            }
        } else if (tid < 96) {
            // action prior: AT[a][s] (LDS only, feeds RA)
            const int s = tid - 64;
            const float* row = params_a_s + s * A_N;
            float p[8];
            #pragma unroll
            for (int i = 0; i < 2; ++i) {
                float4 v = reinterpret_cast<const float4*>(row)[i];
                p[4*i]=v.x; p[4*i+1]=v.y; p[4*i+2]=v.z; p[4*i+3]=v.w;
            }
            float mx = p[0];
            #pragma unroll
            for (int i = 1; i < 8; ++i) mx = fmaxf(mx, p[i]);
            float sum = 0.f;
            #pragma unroll
            for (int i = 0; i < 8; ++i) { p[i] = __expf(p[i] - mx); sum += p[i]; }
            const float inv = 1.0f / sum;
            #pragma unroll
            for (int a = 0; a < 8; ++a) sAT[a * 32 + s] = p[a] * inv;
        } else if (tid < 128) {
            // pi = softmax(params_s): redundant compute, write own element
            const int s = tid - 96;
            float p[32];
            #pragma unroll
            for (int i = 0; i < 8; ++i) {
                float4 v = reinterpret_cast<const float4*>(params_s)[i];
                p[4*i]=v.x; p[4*i+1]=v.y; p[4*i+2]=v.z; p[4*i+3]=v.w;
            }
            float mx = p[0];
            #pragma unroll
            for (int i = 1; i < 32; ++i) mx = fmaxf(mx, p[i]);
            float sum = 0.f;
            #pragma unroll
            for (int i = 0; i < 32; ++i) { p[i] = __expf(p[i] - mx); sum += p[i]; }
            ws[PI_OFF + s] = p[s] / sum;
        }
        __syncthreads();
        // RA[r*8+a][s] = RT[r][s] * AT[a][s]
        #pragma unroll 1
        for (int i = tid; i < 2048; i += 256) {
            const int sl = i & 31, ra = i >> 5;
            ws[RA_OFF + i] = sRT[(ra >> 3) * 32 + sl] * sAT[(ra & 7) * 32 + sl];
        }
    }
}

#define RLI(v, l) __builtin_amdgcn_readlane((v), (l))

// Load action A_'s two T B-frags (dest halves): 2 x ds_read_b128, prefetchable
#define LOADT(TH0, TH1, A_) {                                                \
    const bf16x8* p_ = reinterpret_cast<const bf16x8*>(sTH + ((A_) << 7));   \
    TH0 = p_[lane];                                                          \
    TH1 = p_[lane + 64]; }

// Emission factors for the step encoded in the low 16 bits of PKW (from LDS)
#define LOADE(EO, ERA, PKW) {                                                \
    const unsigned pk_ = (PKW);                                              \
    EO  = sE[(int)(pk_ & 63u) * 32 + sl];                                    \
    ERA = sE[eBase + (int)((pk_ >> 6) & 7u) * eMulR                          \
                   + (int)((pk_ >> 9) & 7u) * eMulA + sl]; }

// One HMM step on the MATRIX CORE:
//   w = u*E (per-lane, same layout as r3..r12) -> bounce through per-wave LDS
//   so each lane picks up its A-frag k-octet (8 consecutive w's) -> pack to
//   bf16 (r12-validated +0x8000 rounding) -> two independent
//   mfma_f32_16x16x32_bf16 (B = T_a's two dest-halves, A = w replicated over
//   rows so EVERY row of D equals u') -> u'[lane&31] via one cndmask.
#define STEP(EO, ERA, TH0, TH1) {                                            \
    const float wv = u * (EO) * (ERA);                                       \
    swv[sl] = wv;                                                            \
    const float4 wa = *reinterpret_cast<const float4*>(swv + 8 * g);         \
    const float4 wb = *reinterpret_cast<const float4*>(swv + 8 * g + 4);     \
    union { int i[4]; bf16x8 v; } A_;                                        \
    A_.i[0] = (int)(((__float_as_uint(wa.x) + 0x8000u) >> 16) |              \
                    ((__float_as_uint(wa.y) + 0x8000u) & 0xffff0000u));      \
    A_.i[1] = (int)(((__float_as_uint(wa.z) + 0x8000u) >> 16) |              \
                    ((__float_as_uint(wa.w) + 0x8000u) & 0xffff0000u));      \
    A_.i[2] = (int)(((__float_as_uint(wb.x) + 0x8000u) >> 16) |              \
                    ((__float_as_uint(wb.y) + 0x8000u) & 0xffff0000u));      \
    A_.i[3] = (int)(((__float_as_uint(wb.z) + 0x8000u) >> 16) |              \
                    ((__float_as_uint(wb.w) + 0x8000u) & 0xffff0000u));      \
    const f32x4 d0 = __builtin_amdgcn_mfma_f32_16x16x32_bf16(A_.v, TH0, zf4, 0, 0, 0); \
    const f32x4 d1 = __builtin_amdgcn_mfma_f32_16x16x32_bf16(A_.v, TH1, zf4, 0, 0, 0); \
    u = (lane & 16) ? d1[0] : d0[0];                                         \
}

// exact power-of-two rescale every 2 steps (validated r3..r12 scheme)
#define RESCALE() {                                                          \
    const int ub = RLI(__float_as_int(u), 0);                                \
    const int kb = (ub >> 23) & 255;                                         \
    u *= __int_as_float((254 - kb) << 23);                                   \
    ksum += kb - 127; }

// 4 waves per block, ONE episode per wave, shared LDS tables. r6 depth-1
// prefetch A/B loop with the MFMA step core.
__global__ __launch_bounds__(256) void tam_main(
    const float* __restrict__ regime,
    const int*   __restrict__ obs,
    const int*   __restrict__ rewards,
    const int*   __restrict__ dones_i,   // float32 0/1 read as int bits
    const int*   __restrict__ actions,
    const float* __restrict__ ws,
    float* __restrict__ out)
{
    __shared__ uint4 sTH[1024];          // 16 KB bf16 T in B-frag layout
    __shared__ float sE[L_N];            // 17.1 KB emission block
    __shared__ float sWB[4][32];         // per-wave w bounce buffers
    const int tid  = threadIdx.x;
    const int lane = tid & 63;
    const int wid  = tid >> 6;
    const int sl   = lane & 31;
    const int g    = lane >> 4;          // A-frag k-octet group (0..3)
    const int b    = blockIdx.x * 4 + wid;
    float* swv = sWB[wid];
    const f32x4 zf4 = {0.f, 0.f, 0.f, 0.f};

    // stage T (16 KB) and emissions (17.1 KB) into LDS — 256 threads
    {
        const uint4* gt = reinterpret_cast<const uint4*>(ws);
        #pragma unroll
        for (int i = 0; i < 4; ++i) sTH[tid + i * 256] = gt[tid + i * 256];
        const float4* ge = reinterpret_cast<const float4*>(ws + OT_OFF);
        float4* s4 = reinterpret_cast<float4*>(sE);
        #pragma unroll 1
        for (int i = tid; i < L_N / 4; i += 256) s4[i] = ge[i];
    }
    __syncthreads();

    // per-lane packed step-pair indices: lane i holds steps 2i (low16), 2i+1 (high16)
    const int t0 = 2 * lane, t1 = 2 * lane + 1;
    const int o0 = obs[t0 * B_N + b],      o1 = obs[t1 * B_N + b];
    const int r0 = rewards[t0 * B_N + b],  r1 = rewards[t1 * B_N + b];
    const int a0 = actions[t0 * B_N + b],  a1 = actions[t1 * B_N + b];
    const int d0i = dones_i[t0 * B_N + b], d1i = dones_i[t1 * B_N + b];
    const int vpk = (o0 | (r0 << 6) | (a0 << 9)) |
                    ((o1 | (r1 << 6) | (a1 << 9)) << 16);

    // first-done step t* via ballot (per-wave; no done checks in the hot loop)
    const unsigned long long mEv = __ballot(d0i != 0);
    const unsigned long long mOd = __ballot(d1i != 0);
    const int tE = mEv ? 2 * __builtin_ctzll(mEv)     : (1 << 30);
    const int tO = mOd ? 2 * __builtin_ctzll(mOd) + 1 : (1 << 30);
    const int tstar  = tE < tO ? tE : tO;
    const int nsteps = tstar < 128 ? tstar : 128;

    // regime==1 -> action term excluded every step: use RT table (a ignored)
    const bool skipA = (regime[b] == 1.0f);
    const int eBase = skipA ? L_RT : L_RA;
    const int eMulR = skipA ? 32 : 256;
    const int eMulA = skipA ? 0 : 32;

    float u = sE[L_PI + sl];
    int ksum = 0;
    float eoA, eraA, eoB, eraB;
    bf16x8 thA0, thA1, thB0, thB1;

    unsigned pkc = (unsigned)RLI(vpk, 0);
    unsigned pkn = (unsigned)RLI(vpk, 1);
    LOADE(eoA, eraA, pkc & 0xffffu);
    LOADT(thA0, thA1, (int)((pkc >> 9) & 7u));

    const int npairs = nsteps >> 1;
    #pragma unroll 1
    for (int i = 0; i < npairs; ++i) {
        // prefetch step 2i+1 (B), compute step 2i (A)
        LOADE(eoB, eraB, pkc >> 16);
        LOADT(thB0, thB1, (int)((pkc >> 25) & 7u));
        STEP(eoA, eraA, thA0, thA1);
        // prefetch step 2i+2 (next A), compute step 2i+1 (B)
        LOADE(eoA, eraA, pkn & 0xffffu);
        LOADT(thA0, thA1, (int)((pkn >> 9) & 7u));
        STEP(eoB, eraB, thB0, thB1);
        // rotate packed indices (readlane lane wraps mod 64; overflow unused)
        pkc = pkn;
        pkn = (unsigned)RLI(vpk, i + 2);
        RESCALE();
    }

    if (nsteps & 1) {           // leftover even-index step (data already staged)
        STEP(eoA, eraA, thA0, thA1);
    }

    // terminal contribution at e = min(t*, 128): OT*RT only (no action term)
    {
        const int e  = nsteps;
        const int oe = obs[e * B_N + b];
        const int re = rewards[e * B_N + b];
        const float eo = sE[L_OT + oe * 32 + sl];
        const float rt = sE[L_RT + re * 32 + sl];
        float t = u * eo * rt;
        t += __shfl_xor(t, 1, 32);
        t += __shfl_xor(t, 2, 32);
        t += __shfl_xor(t, 4, 32);
        t += __shfl_xor(t, 8, 32);
        t += __shfl_xor(t, 16, 32);
        const float result = (float)ksum * 0.69314718055994531f + __logf(t);
        if (lane == 0) out[b] = result;
    }
}

extern "C" void kernel_launch(void* const* d_in, const int* in_sizes, int n_in,
                              void* d_out, int out_size, void* d_ws, size_t ws_size,
                              hipStream_t stream) {
    (void)in_sizes; (void)n_in; (void)out_size; (void)ws_size;
    const float* regime      = (const float*)d_in[0];
    const int*   obs         = (const int*)d_in[1];
    const int*   rewards     = (const int*)d_in[2];
    const int*   dones_i     = (const int*)d_in[3];
    const int*   actions     = (const int*)d_in[4];
    const float* params_s    = (const float*)d_in[5];
    const float* params_s_sa = (const float*)d_in[6];
    const float* params_o_s  = (const float*)d_in[7];
    const float* params_r_s  = (const float*)d_in[8];
    const float* params_a_s  = (const float*)d_in[9];
    float* ws  = (float*)d_ws;
    float* out = (float*)d_out;

    tam_prep<<<2, 256, 0, stream>>>(params_s, params_s_sa, params_o_s,
                                    params_r_s, params_a_s, ws);
    tam_main<<<256, 256, 0, stream>>>(regime, obs, rewards, dones_i, actions, ws, out);
}

// Round 15
// 29.108 us; speedup vs baseline: 8.4020x; 1.1119x over previous
//
#include <hip/hip_runtime.h>

// Problem constants (fixed by the reference)
#define S_N 32
#define O_N 64
#define A_N 8
#define R_N 8
#define B_N 1024
#define T_N 128

// Workspace layout (float-index offsets):
//  [0, 4096)      TB : bf16 transitions in MFMA B-fragment layout (16 KB).
//                 For action a, frag f (=dest half), lane l (0..63):
//                 uint4 at [a*128 + f*64 + l] holds 8 bf16, elem j =
//                 T[src = 8*(l>>4)+j][a][dest = (l&15)+16f]
//  [4096, 6144)   OT[o][s]     = P(o|s)
//  [6144, 8192)   RA[r*8+a][s] = P(r|s)*P(a|s)
//  [8192, 8448)   RT[r][s]     = P(r|s)
//  [8448, 8480)   PI[s]
#define OT_OFF   4096
#define RA_OFF   6144
#define RT_OFF   8192
#define PI_OFF   8448

// LDS emission block (floats) — contiguous image of ws[4096..8480)
#define L_OT 0
#define L_RA 2048
#define L_RT 4096
#define L_PI 4352
#define L_N  4384

typedef float f32x4 __attribute__((ext_vector_type(4)));
typedef short bf16x8 __attribute__((ext_vector_type(8)));

__global__ __launch_bounds__(256) void tam_prep(
    const float* __restrict__ params_s,
    const float* __restrict__ params_s_sa,
    const float* __restrict__ params_o_s,
    const float* __restrict__ params_r_s,
    const float* __restrict__ params_a_s,
    float* __restrict__ ws)
{
    const int tid = threadIdx.x;
    if (blockIdx.x == 0) {
        // Transitions: one (s,a) row softmax each; scatter bf16 into the
        // MFMA B-frag layout described above.
        const int s = tid >> 3, a = tid & 7;
        const float* row = params_s_sa + (s * A_N + a) * S_N;
        float p[32];
        #pragma unroll
        for (int i = 0; i < 8; ++i) {
            float4 v = reinterpret_cast<const float4*>(row)[i];
            p[4*i]=v.x; p[4*i+1]=v.y; p[4*i+2]=v.z; p[4*i+3]=v.w;
        }
        float mx = p[0];
        #pragma unroll
        for (int i = 1; i < 32; ++i) mx = fmaxf(mx, p[i]);
        float sum = 0.f;
        #pragma unroll
        for (int i = 0; i < 32; ++i) { p[i] = __expf(p[i] - mx); sum += p[i]; }
        const float inv = 1.0f / sum;
        unsigned short* wsh = reinterpret_cast<unsigned short*>(ws);
        #pragma unroll
        for (int d = 0; d < 32; ++d) {
            const unsigned bits = __float_as_uint(p[d] * inv) + 0x8000u;
            const int idx = ((a * 2 + (d >> 4)) * 64 + 16 * (s >> 3) + (d & 15)) * 8
                            + (s & 7);
            wsh[idx] = (unsigned short)(bits >> 16);
        }
    } else {
        __shared__ float sRT[256], sAT[256];
        if (tid < 32) {
            // observation emission: softmax over O (64) per state; OT[o][s]
            const int s = tid;
            const float* row = params_o_s + s * O_N;
            float p[64];
            #pragma unroll
            for (int i = 0; i < 16; ++i) {
                float4 v = reinterpret_cast<const float4*>(row)[i];
                p[4*i]=v.x; p[4*i+1]=v.y; p[4*i+2]=v.z; p[4*i+3]=v.w;
            }
            float mx = p[0];
            #pragma unroll
            for (int i = 1; i < 64; ++i) mx = fmaxf(mx, p[i]);
            float sum = 0.f;
            #pragma unroll
            for (int i = 0; i < 64; ++i) { p[i] = __expf(p[i] - mx); sum += p[i]; }
            const float inv = 1.0f / sum;
            #pragma unroll
            for (int o = 0; o < 64; ++o) ws[OT_OFF + o * 32 + s] = p[o] * inv;
        } else if (tid < 64) {
            // reward emission: RT[r][s]
            const int s = tid - 32;
            const float* row = params_r_s + s * R_N;
            float p[8];
            #pragma unroll
            for (int i = 0; i < 2; ++i) {
                float4 v = reinterpret_cast<const float4*>(row)[i];
                p[4*i]=v.x; p[4*i+1]=v.y; p[4*i+2]=v.z; p[4*i+3]=v.w;
            }
            float mx = p[0];
            #pragma unroll
            for (int i = 1; i < 8; ++i) mx = fmaxf(mx, p[i]);
            float sum = 0.f;
            #pragma unroll
            for (int i = 0; i < 8; ++i) { p[i] = __expf(p[i] - mx); sum += p[i]; }
            const float inv = 1.0f / sum;
            #pragma unroll
            for (int r = 0; r < 8; ++r) {
                const float v = p[r] * inv;
                ws[RT_OFF + r * 32 + s] = v;
                sRT[r * 32 + s] = v;
            }
        } else if (tid < 96) {
            // action prior: AT[a][s] (LDS only, feeds RA)
            const int s = tid - 64;
            const float* row = params_a_s + s * A_N;
            float p[8];
            #pragma unroll
            for (int i = 0; i < 2; ++i) {
                float4 v = reinterpret_cast<const float4*>(row)[i];
                p[4*i]=v.x; p[4*i+1]=v.y; p[4*i+2]=v.z; p[4*i+3]=v.w;
            }
            float mx = p[0];
            #pragma unroll
            for (int i = 1; i < 8; ++i) mx = fmaxf(mx, p[i]);
            float sum = 0.f;
            #pragma unroll
            for (int i = 0; i < 8; ++i) { p[i] = __expf(p[i] - mx); sum += p[i]; }
            const float inv = 1.0f / sum;
            #pragma unroll
            for (int a = 0; a < 8; ++a) sAT[a * 32 + s] = p[a] * inv;
        } else if (tid < 128) {
            // pi = softmax(params_s): redundant compute, write own element
            const int s = tid - 96;
            float p[32];
            #pragma unroll
            for (int i = 0; i < 8; ++i) {
                float4 v = reinterpret_cast<const float4*>(params_s)[i];
                p[4*i]=v.x; p[4*i+1]=v.y; p[4*i+2]=v.z; p[4*i+3]=v.w;
            }
            float mx = p[0];
            #pragma unroll
            for (int i = 1; i < 32; ++i) mx = fmaxf(mx, p[i]);
            float sum = 0.f;
            #pragma unroll
            for (int i = 0; i < 32; ++i) { p[i] = __expf(p[i] - mx); sum += p[i]; }
            ws[PI_OFF + s] = p[s] / sum;
        }
        __syncthreads();
        // RA[r*8+a][s] = RT[r][s] * AT[a][s]
        #pragma unroll 1
        for (int i = tid; i < 2048; i += 256) {
            const int sl = i & 31, ra = i >> 5;
            ws[RA_OFF + i] = sRT[(ra >> 3) * 32 + sl] * sAT[(ra & 7) * 32 + sl];
        }
    }
}

#define RLI(v, l) __builtin_amdgcn_readlane((v), (l))

// Load action A_'s two T B-frags (dest halves): 2 x ds_read_b128, prefetchable
#define LOADT(TH0, TH1, A_) {                                                \
    const bf16x8* p_ = reinterpret_cast<const bf16x8*>(sTH + ((A_) << 7));   \
    TH0 = p_[lane];                                                          \
    TH1 = p_[lane + 64]; }

// Emission factor product for the step in the low 16 bits of PKW (from LDS);
// the eo*era multiply is OFF the u-dependency path (done at prefetch time).
#define LOADE(E, PKW) {                                                      \
    const unsigned pk_ = (PKW);                                              \
    const float eo_  = sE[(int)(pk_ & 63u) * 32 + sl];                       \
    const float era_ = sE[eBase + (int)((pk_ >> 6) & 7u) * eMulR             \
                        + (int)((pk_ >> 9) & 7u) * eMulA + sl];              \
    E = eo_ * era_; }

// One HMM step on the MATRIX CORE, A-frag built by ds_bpermute (no LDS
// write->read bounce): the DPP quad-swap pack (r12-validated) leaves the
// dword (bf16 w[2k], bf16 w[2k+1]) at even lane 2k; lane l's A-frag dword m
// is exactly that dword at source lane 8g+2m (g = l>>4) -> 4 bpermute pulls,
// zero assembly. Then 2 independent mfma_f32_16x16x32_bf16 (B = T_a's two
// dest-halves; A rows identical so every row of D = u') and 1 cndmask.
#define STEP(E, TH0, TH1) {                                                  \
    const float wv = u * (E);                                                \
    const int wvb = __float_as_int(wv) + 0x8000;                             \
    const int wpb = __builtin_amdgcn_mov_dpp(wvb, 0xB1, 0xF, 0xF, true);     \
    const int whi = (int)(((unsigned)wvb >> 16) |                            \
                          ((unsigned)wpb & 0xffff0000u));                    \
    union { int i[4]; bf16x8 v; } A_;                                        \
    A_.i[0] = __builtin_amdgcn_ds_bpermute(bpb,      whi);                   \
    A_.i[1] = __builtin_amdgcn_ds_bpermute(bpb + 8,  whi);                   \
    A_.i[2] = __builtin_amdgcn_ds_bpermute(bpb + 16, whi);                   \
    A_.i[3] = __builtin_amdgcn_ds_bpermute(bpb + 24, whi);                   \
    const f32x4 d0 = __builtin_amdgcn_mfma_f32_16x16x32_bf16(A_.v, TH0, zf4, 0, 0, 0); \
    const f32x4 d1 = __builtin_amdgcn_mfma_f32_16x16x32_bf16(A_.v, TH1, zf4, 0, 0, 0); \
    u = (lane & 16) ? d1[0] : d0[0];                                         \
}

// exact power-of-two rescale every 2 steps (validated r3..r14 scheme)
#define RESCALE() {                                                          \
    const int ub = RLI(__float_as_int(u), 0);                                \
    const int kb = (ub >> 23) & 255;                                         \
    u *= __int_as_float((254 - kb) << 23);                                   \
    ksum += kb - 127; }

// 4 waves per block, ONE episode per wave, shared LDS tables. r6 depth-1
// prefetch A/B loop with the MFMA+bpermute step core.
__global__ __launch_bounds__(256) void tam_main(
    const float* __restrict__ regime,
    const int*   __restrict__ obs,
    const int*   __restrict__ rewards,
    const int*   __restrict__ dones_i,   // float32 0/1 read as int bits
    const int*   __restrict__ actions,
    const float* __restrict__ ws,
    float* __restrict__ out)
{
    __shared__ uint4 sTH[1024];          // 16 KB bf16 T in B-frag layout
    __shared__ float sE[L_N];            // 17.1 KB emission block
    const int tid  = threadIdx.x;
    const int lane = tid & 63;
    const int wid  = tid >> 6;
    const int sl   = lane & 31;
    const int bpb  = (lane >> 4) * 32;   // bpermute byte addr of lane 8g
    const int b    = blockIdx.x * 4 + wid;
    const f32x4 zf4 = {0.f, 0.f, 0.f, 0.f};

    // stage T (16 KB) and emissions (17.1 KB) into LDS — 256 threads
    {
        const uint4* gt = reinterpret_cast<const uint4*>(ws);
        #pragma unroll
        for (int i = 0; i < 4; ++i) sTH[tid + i * 256] = gt[tid + i * 256];
        const float4* ge = reinterpret_cast<const float4*>(ws + OT_OFF);
        float4* s4 = reinterpret_cast<float4*>(sE);
        #pragma unroll 1
        for (int i = tid; i < L_N / 4; i += 256) s4[i] = ge[i];
    }
    __syncthreads();

    // per-lane packed step-pair indices: lane i holds steps 2i (low16), 2i+1 (high16)
    const int t0 = 2 * lane, t1 = 2 * lane + 1;
    const int o0 = obs[t0 * B_N + b],      o1 = obs[t1 * B_N + b];
    const int r0 = rewards[t0 * B_N + b],  r1 = rewards[t1 * B_N + b];
    const int a0 = actions[t0 * B_N + b],  a1 = actions[t1 * B_N + b];
    const int d0i = dones_i[t0 * B_N + b], d1i = dones_i[t1 * B_N + b];
    const int vpk = (o0 | (r0 << 6) | (a0 << 9)) |
                    ((o1 | (r1 << 6) | (a1 << 9)) << 16);

    // first-done step t* via ballot (per-wave; no done checks in the hot loop)
    const unsigned long long mEv = __ballot(d0i != 0);
    const unsigned long long mOd = __ballot(d1i != 0);
    const int tE = mEv ? 2 * __builtin_ctzll(mEv)     : (1 << 30);
    const int tO = mOd ? 2 * __builtin_ctzll(mOd) + 1 : (1 << 30);
    const int tstar  = tE < tO ? tE : tO;
    const int nsteps = tstar < 128 ? tstar : 128;

    // regime==1 -> action term excluded every step: use RT table (a ignored)
    const bool skipA = (regime[b] == 1.0f);
    const int eBase = skipA ? L_RT : L_RA;
    const int eMulR = skipA ? 32 : 256;
    const int eMulA = skipA ? 0 : 32;

    float u = sE[L_PI + sl];
    int ksum = 0;
    float eA, eB;
    bf16x8 thA0, thA1, thB0, thB1;

    unsigned pkc = (unsigned)RLI(vpk, 0);
    unsigned pkn = (unsigned)RLI(vpk, 1);
    LOADE(eA, pkc & 0xffffu);
    LOADT(thA0, thA1, (int)((pkc >> 9) & 7u));

    const int npairs = nsteps >> 1;
    #pragma unroll 1
    for (int i = 0; i < npairs; ++i) {
        // prefetch step 2i+1 (B), compute step 2i (A)
        LOADE(eB, pkc >> 16);
        LOADT(thB0, thB1, (int)((pkc >> 25) & 7u));
        STEP(eA, thA0, thA1);
        // prefetch step 2i+2 (next A), compute step 2i+1 (B)
        LOADE(eA, pkn & 0xffffu);
        LOADT(thA0, thA1, (int)((pkn >> 9) & 7u));
        STEP(eB, thB0, thB1);
        // rotate packed indices (readlane lane wraps mod 64; overflow unused)
        pkc = pkn;
        pkn = (unsigned)RLI(vpk, i + 2);
        RESCALE();
    }

    if (nsteps & 1) {           // leftover even-index step (data already staged)
        STEP(eA, thA0, thA1);
    }

    // terminal contribution at e = min(t*, 128): OT*RT only (no action term)
    {
        const int e  = nsteps;
        const int oe = obs[e * B_N + b];
        const int re = rewards[e * B_N + b];
        const float eo = sE[L_OT + oe * 32 + sl];
        const float rt = sE[L_RT + re * 32 + sl];
        float t = u * eo * rt;
        t += __shfl_xor(t, 1, 32);
        t += __shfl_xor(t, 2, 32);
        t += __shfl_xor(t, 4, 32);
        t += __shfl_xor(t, 8, 32);
        t += __shfl_xor(t, 16, 32);
        const float result = (float)ksum * 0.69314718055994531f + __logf(t);
        if (lane == 0) out[b] = result;
    }
}

extern "C" void kernel_launch(void* const* d_in, const int* in_sizes, int n_in,
                              void* d_out, int out_size, void* d_ws, size_t ws_size,
                              hipStream_t stream) {
    (void)in_sizes; (void)n_in; (void)out_size; (void)ws_size;
    const float* regime      = (const float*)d_in[0];
    const int*   obs         = (const int*)d_in[1];
    const int*   rewards     = (const int*)d_in[2];
    const int*   dones_i     = (const int*)d_in[3];
    const int*   actions     = (const int*)d_in[4];
    const float* params_s    = (const float*)d_in[5];
    const float* params_s_sa = (const float*)d_in[6];
    const float* params_o_s  = (const float*)d_in[7];
    const float* params_r_s  = (const float*)d_in[8];
    const float* params_a_s  = (const float*)d_in[9];
    float* ws  = (float*)d_ws;
    float* out = (float*)d_out;

    tam_prep<<<2, 256, 0, stream>>>(params_s, params_s_sa, params_o_s,
                                    params_r_s, params_a_s, ws);
    tam_main<<<256, 256, 0, stream>>>(regime, obs, rewards, dones_i, actions, ws, out);
}

// Round 16
// 26.329 us; speedup vs baseline: 9.2887x; 1.1055x over previous
//
#include <hip/hip_runtime.h>

// Problem constants (fixed by the reference)
#define S_N 32
#define O_N 64
#define A_N 8
#define R_N 8
#define B_N 1024
#define T_N 128

// LDS emission block offsets (floats): OT[o][s] | RA[r*8+a][s] | RT[r][s] | PI[s]
#define L_OT 0
#define L_RA 2048
#define L_RT 4096
#define L_PI 4352
#define L_N  4384

typedef float f32x4 __attribute__((ext_vector_type(4)));
typedef short bf16x8 __attribute__((ext_vector_type(8)));

#define RLI(v, l) __builtin_amdgcn_readlane((v), (l))

// Load action A_'s two T B-frags (dest halves): 2 x ds_read_b128, prefetchable
#define LOADT(TH0, TH1, A_) {                                                \
    const bf16x8* p_ = reinterpret_cast<const bf16x8*>(sTH + ((A_) << 7));   \
    TH0 = p_[lane];                                                          \
    TH1 = p_[lane + 64]; }

// Emission factor products for this lane's state pair (h0, h0+16), for the
// step encoded in the low 16 bits of PKW. Off the u-dependency path.
#define LOADE(ELO, EHI, PKW) {                                               \
    const unsigned pk_ = (PKW);                                              \
    const int ob_ = L_OT + (int)(pk_ & 63u) * 32 + h0;                       \
    const int rb_ = eBase + (int)((pk_ >> 6) & 7u) * eMulR                   \
                  + (int)((pk_ >> 9) & 7u) * eMulA + h0;                     \
    ELO = sE[ob_] * sE[rb_];                                                 \
    EHI = sE[ob_ + 16] * sE[rb_ + 16]; }

// One HMM step on the MATRIX CORE with permuted-k state order
// (k-pair (2j,2j+1) = states (j, j+16)): each lane's A-frag pair-word comes
// from its OWN (ulo,uhi) — no cndmask, no DPP. A-frag dword m pulled from
// lane 4g+m via bpermute; two mfma_f32_16x16x32_bf16 give the next
// (ulo,uhi) directly (A rows identical -> every D row = u').
#define STEP(ELO, EHI, TH0, TH1) {                                           \
    const float wlo = ulo * (ELO), whi = uhi * (EHI);                        \
    const int ilo = __float_as_int(wlo) + 0x8000;                            \
    const int ihi = __float_as_int(whi) + 0x8000;                            \
    const int pw = (int)(((unsigned)ilo >> 16) | ((unsigned)ihi & 0xffff0000u)); \
    union { int i[4]; bf16x8 v; } A_;                                        \
    A_.i[0] = __builtin_amdgcn_ds_bpermute(bpb,      pw);                    \
    A_.i[1] = __builtin_amdgcn_ds_bpermute(bpb + 4,  pw);                    \
    A_.i[2] = __builtin_amdgcn_ds_bpermute(bpb + 8,  pw);                    \
    A_.i[3] = __builtin_amdgcn_ds_bpermute(bpb + 12, pw);                    \
    const f32x4 d0 = __builtin_amdgcn_mfma_f32_16x16x32_bf16(A_.v, TH0, zf4, 0, 0, 0); \
    const f32x4 d1 = __builtin_amdgcn_mfma_f32_16x16x32_bf16(A_.v, TH1, zf4, 0, 0, 0); \
    ulo = d0[0]; uhi = d1[0];                                                \
}

// exact power-of-two rescale every 2 steps (validated scheme; state-0 proxy)
#define RESCALE() {                                                          \
    const int ub = RLI(__float_as_int(ulo), 0);                              \
    const int kb = (ub >> 23) & 255;                                         \
    const float sc_ = __int_as_float((254 - kb) << 23);                      \
    ulo *= sc_; uhi *= sc_;                                                  \
    ksum += kb - 127; }

// SINGLE fused kernel: per-block LDS table build (no prep launch), then the
// r15 depth-1 prefetch A/B loop with the permuted-k MFMA step core.
// 4 waves per block, ONE episode per wave.
__global__ __launch_bounds__(256) void tam_fused(
    const float* __restrict__ regime,
    const int*   __restrict__ obs,
    const int*   __restrict__ rewards,
    const int*   __restrict__ dones_i,   // float32 0/1 read as int bits
    const int*   __restrict__ actions,
    const float* __restrict__ params_s,
    const float* __restrict__ params_s_sa,
    const float* __restrict__ params_o_s,
    const float* __restrict__ params_r_s,
    const float* __restrict__ params_a_s,
    float* __restrict__ out)
{
    __shared__ uint4 sTH[1024];          // 16 KB bf16 T, B-frag permuted-k layout
    __shared__ float sE[L_N];            // 17.1 KB emission block
    __shared__ float sAT[256];           // action prior (feeds RA)
    const int tid  = threadIdx.x;
    const int lane = tid & 63;
    const int wid  = tid >> 6;
    const int h0   = lane & 15;          // this lane's low state
    const int g    = lane >> 4;          // A-frag k-octet group (0..3)
    const int bpb  = g * 16;             // bpermute byte addr of src lane 4g
    const int b    = blockIdx.x * 4 + wid;
    const f32x4 zf4 = {0.f, 0.f, 0.f, 0.f};

    // ---------- Phase 1: build tables in LDS (concurrent thread split) ----
    if (tid < 128) {
        // two transition-row softmaxes each; scatter bf16 into the B-frag
        // layout with permuted k: row s sits at k = 2*(s&15) + (s>>4).
        unsigned short* sTHh = reinterpret_cast<unsigned short*>(sTH);
        #pragma unroll 1
        for (int rr = 0; rr < 2; ++rr) {
            const int idx = 2 * tid + rr;
            const int s = idx >> 3, a = idx & 7;
            const float* row = params_s_sa + (s * A_N + a) * S_N;
            float p[32];
            #pragma unroll
            for (int i = 0; i < 8; ++i) {
                float4 v = reinterpret_cast<const float4*>(row)[i];
                p[4*i]=v.x; p[4*i+1]=v.y; p[4*i+2]=v.z; p[4*i+3]=v.w;
            }
            float mx = p[0];
            #pragma unroll
            for (int i = 1; i < 32; ++i) mx = fmaxf(mx, p[i]);
            float sum = 0.f;
            #pragma unroll
            for (int i = 0; i < 32; ++i) { p[i] = __expf(p[i] - mx); sum += p[i]; }
            const float inv = 1.0f / sum;
            const int ks = 2 * (s & 15) + (s >> 4);
            const int gk = ks >> 3, e8 = ks & 7;
            #pragma unroll
            for (int d = 0; d < 32; ++d) {
                const unsigned bits = __float_as_uint(p[d] * inv) + 0x8000u;
                const int l2 = 16 * gk + (d & 15);
                sTHh[((a * 2 + (d >> 4)) * 64 + l2) * 8 + e8] =
                    (unsigned short)(bits >> 16);
            }
        }
    } else {
        const int e = tid - 128;
        if (e < 32) {
            // observation emission: softmax over O (64); OT[o][s]
            const int s = e;
            const float* row = params_o_s + s * O_N;
            float p[64];
            #pragma unroll
            for (int i = 0; i < 16; ++i) {
                float4 v = reinterpret_cast<const float4*>(row)[i];
                p[4*i]=v.x; p[4*i+1]=v.y; p[4*i+2]=v.z; p[4*i+3]=v.w;
            }
            float mx = p[0];
            #pragma unroll
            for (int i = 1; i < 64; ++i) mx = fmaxf(mx, p[i]);
            float sum = 0.f;
            #pragma unroll
            for (int i = 0; i < 64; ++i) { p[i] = __expf(p[i] - mx); sum += p[i]; }
            const float inv = 1.0f / sum;
            #pragma unroll
            for (int o = 0; o < 64; ++o) sE[L_OT + o * 32 + s] = p[o] * inv;
        } else if (e < 64) {
            // reward emission: RT[r][s]
            const int s = e - 32;
            const float* row = params_r_s + s * R_N;
            float p[8];
            #pragma unroll
            for (int i = 0; i < 2; ++i) {
                float4 v = reinterpret_cast<const float4*>(row)[i];
                p[4*i]=v.x; p[4*i+1]=v.y; p[4*i+2]=v.z; p[4*i+3]=v.w;
            }
            float mx = p[0];
            #pragma unroll
            for (int i = 1; i < 8; ++i) mx = fmaxf(mx, p[i]);
            float sum = 0.f;
            #pragma unroll
            for (int i = 0; i < 8; ++i) { p[i] = __expf(p[i] - mx); sum += p[i]; }
            const float inv = 1.0f / sum;
            #pragma unroll
            for (int r = 0; r < 8; ++r) sE[L_RT + r * 32 + s] = p[r] * inv;
        } else if (e < 96) {
            // action prior: AT[a][s] (feeds RA only)
            const int s = e - 64;
            const float* row = params_a_s + s * A_N;
            float p[8];
            #pragma unroll
            for (int i = 0; i < 2; ++i) {
                float4 v = reinterpret_cast<const float4*>(row)[i];
                p[4*i]=v.x; p[4*i+1]=v.y; p[4*i+2]=v.z; p[4*i+3]=v.w;
            }
            float mx = p[0];
            #pragma unroll
            for (int i = 1; i < 8; ++i) mx = fmaxf(mx, p[i]);
            float sum = 0.f;
            #pragma unroll
            for (int i = 0; i < 8; ++i) { p[i] = __expf(p[i] - mx); sum += p[i]; }
            const float inv = 1.0f / sum;
            #pragma unroll
            for (int a = 0; a < 8; ++a) sAT[a * 32 + s] = p[a] * inv;
        } else {
            // pi = softmax(params_s): redundant per-thread, write own element
            const int s = e - 96;
            float p[32];
            #pragma unroll
            for (int i = 0; i < 8; ++i) {
                float4 v = reinterpret_cast<const float4*>(params_s)[i];
                p[4*i]=v.x; p[4*i+1]=v.y; p[4*i+2]=v.z; p[4*i+3]=v.w;
            }
            float mx = p[0];
            #pragma unroll
            for (int i = 1; i < 32; ++i) mx = fmaxf(mx, p[i]);
            float sum = 0.f;
            #pragma unroll
            for (int i = 0; i < 32; ++i) { p[i] = __expf(p[i] - mx); sum += p[i]; }
            sE[L_PI + s] = p[s] / sum;
        }
    }
    __syncthreads();
    // RA[r*8+a][s] = RT[r][s] * AT[a][s]
    #pragma unroll 1
    for (int i = tid; i < 2048; i += 256) {
        const int sl2 = i & 31, ra = i >> 5;
        sE[L_RA + i] = sE[L_RT + (ra >> 3) * 32 + sl2] * sAT[(ra & 7) * 32 + sl2];
    }
    __syncthreads();

    // ---------- Phase 2: forward filter (r15 loop, permuted-k MFMA core) --
    // per-lane packed step-pair indices: lane i holds steps 2i (low16), 2i+1 (high16)
    const int t0 = 2 * lane, t1 = 2 * lane + 1;
    const int o0 = obs[t0 * B_N + b],      o1 = obs[t1 * B_N + b];
    const int r0 = rewards[t0 * B_N + b],  r1 = rewards[t1 * B_N + b];
    const int a0 = actions[t0 * B_N + b],  a1 = actions[t1 * B_N + b];
    const int d0i = dones_i[t0 * B_N + b], d1i = dones_i[t1 * B_N + b];
    const int vpk = (o0 | (r0 << 6) | (a0 << 9)) |
                    ((o1 | (r1 << 6) | (a1 << 9)) << 16);

    // first-done step t* via ballot (per-wave; no done checks in hot loop)
    const unsigned long long mEv = __ballot(d0i != 0);
    const unsigned long long mOd = __ballot(d1i != 0);
    const int tE = mEv ? 2 * __builtin_ctzll(mEv)     : (1 << 30);
    const int tO = mOd ? 2 * __builtin_ctzll(mOd) + 1 : (1 << 30);
    const int tstar  = tE < tO ? tE : tO;
    const int nsteps = tstar < 128 ? tstar : 128;

    // regime==1 -> action term excluded every step: use RT table (a ignored)
    const bool skipA = (regime[b] == 1.0f);
    const int eBase = skipA ? L_RT : L_RA;
    const int eMulR = skipA ? 32 : 256;
    const int eMulA = skipA ? 0 : 32;

    float ulo = sE[L_PI + h0];
    float uhi = sE[L_PI + h0 + 16];
    int ksum = 0;
    float eloA, ehiA, eloB, ehiB;
    bf16x8 thA0, thA1, thB0, thB1;

    unsigned pkc = (unsigned)RLI(vpk, 0);
    unsigned pkn = (unsigned)RLI(vpk, 1);
    LOADE(eloA, ehiA, pkc & 0xffffu);
    LOADT(thA0, thA1, (int)((pkc >> 9) & 7u));

    const int npairs = nsteps >> 1;
    #pragma unroll 1
    for (int i = 0; i < npairs; ++i) {
        // prefetch step 2i+1 (B), compute step 2i (A)
        LOADE(eloB, ehiB, pkc >> 16);
        LOADT(thB0, thB1, (int)((pkc >> 25) & 7u));
        STEP(eloA, ehiA, thA0, thA1);
        // prefetch step 2i+2 (next A), compute step 2i+1 (B)
        LOADE(eloA, ehiA, pkn & 0xffffu);
        LOADT(thA0, thA1, (int)((pkn >> 9) & 7u));
        STEP(eloB, ehiB, thB0, thB1);
        // rotate packed indices (readlane lane wraps mod 64; overflow unused)
        pkc = pkn;
        pkn = (unsigned)RLI(vpk, i + 2);
        RESCALE();
    }

    if (nsteps & 1) {           // leftover even-index step (data already staged)
        STEP(eloA, ehiA, thA0, thA1);
    }

    // terminal contribution at e = min(t*, 128): OT*RT only (no action term)
    {
        const int e  = nsteps;
        const int oe = obs[e * B_N + b];
        const int re = rewards[e * B_N + b];
        const int ob = L_OT + oe * 32 + h0;
        const int rb = L_RT + re * 32 + h0;
        float t = ulo * sE[ob] * sE[rb] + uhi * sE[ob + 16] * sE[rb + 16];
        t += __shfl_xor(t, 1, 16);
        t += __shfl_xor(t, 2, 16);
        t += __shfl_xor(t, 4, 16);
        t += __shfl_xor(t, 8, 16);
        const float result = (float)ksum * 0.69314718055994531f + __logf(t);
        if (lane == 0) out[b] = result;
    }
}

extern "C" void kernel_launch(void* const* d_in, const int* in_sizes, int n_in,
                              void* d_out, int out_size, void* d_ws, size_t ws_size,
                              hipStream_t stream) {
    (void)in_sizes; (void)n_in; (void)out_size; (void)d_ws; (void)ws_size;
    const float* regime      = (const float*)d_in[0];
    const int*   obs         = (const int*)d_in[1];
    const int*   rewards     = (const int*)d_in[2];
    const int*   dones_i     = (const int*)d_in[3];
    const int*   actions     = (const int*)d_in[4];
    const float* params_s    = (const float*)d_in[5];
    const float* params_s_sa = (const float*)d_in[6];
    const float* params_o_s  = (const float*)d_in[7];
    const float* params_r_s  = (const float*)d_in[8];
    const float* params_a_s  = (const float*)d_in[9];
    float* out = (float*)d_out;

    tam_fused<<<256, 256, 0, stream>>>(regime, obs, rewards, dones_i, actions,
                                       params_s, params_s_sa, params_o_s,
                                       params_r_s, params_a_s, out);
}